// Round 7
// baseline (166.692 us; speedup 1.0000x reference)
//
#include <hip/hip_runtime.h>

// GeoCyclicPadding: x (B=2, C=192, H=360, W=720) f32, p=3 -> out (B,C,366,726)
//
// Wave-per-output-row, BOTH streams 16B-aligned.
// Middle rows (ho=r+3): out row = [x717,x718,x719, x0..x719, x0,x1,x2].
//   Out group g (4 floats at 16g bytes, row base 16B-aligned since
//   2904 B/row % 16 == 0) = {prev.y, prev.z, prev.w, cur.x} with
//   cur = ing[g%180], prev = ing[(g-1)%180]  (ing = aligned float4 groups
//   of the source row). Single rule covers g=0 (prev=ing[179]) through
//   g=181 (float2 {prev.y,prev.z}, prev=ing[0]). prev comes from
//   __shfl_up(cur,1); lane 0 patches with one predicated L1-hot load.
// Halo rows (ho in {0,1,2,363,364,365}, h = 2-hr / 362-hr): same aligned
//   store structure, per-element scalar loads via
//   wr=(c+360)%726, w=(wr-3)%720.  Only 2304 rows (0.8%) -> 576 blocks.

typedef float f4a __attribute__((ext_vector_type(4), aligned(16)));
typedef float f2a __attribute__((ext_vector_type(2), aligned(8)));

__global__ __launch_bounds__(256) void geo_pad_kernel(const float* __restrict__ x,
                                                      float* __restrict__ out) {
    constexpr int W = 720, H = 360, p = 3, Wp = 726, Hp = 366;
    constexpr unsigned MIDROWS = 384u * 360u;     // 138,240
    constexpr unsigned MIDBLK  = MIDROWS / 4u;    // 34,560 blocks (4 waves/block)

    const unsigned wid  = threadIdx.x >> 6;
    const int lane = (int)(threadIdx.x & 63u);

    if (blockIdx.x < MIDBLK) {
        // ---- middle rows: aligned load + shuffle-realign + aligned store ----
        const unsigned row = blockIdx.x * 4u + wid;      // = bc*360 + r
        const unsigned r  = row % 360u;
        const unsigned bc = row / 360u;
        const f4a* __restrict__ sg =
            reinterpret_cast<const f4a*>(x + (size_t)row * W);
        float* __restrict__ orow = out + ((size_t)bc * Hp + (r + 3)) * Wp;

#pragma unroll
        for (int j = 0; j < 3; ++j) {
            const int g = 64 * j + lane;                 // output group
            int gi = g; if (gi >= 180) gi -= 180;        // source group
            f4a cur = __builtin_nontemporal_load(sg + gi);
            float py = __shfl_up(cur.y, 1);
            float pz = __shfl_up(cur.z, 1);
            float pw = __shfl_up(cur.w, 1);
            if (lane == 0) {                             // prev for wave head
                const int pgi = (j == 0) ? 179 : (64 * j - 1);
                f4a pv = *(sg + pgi);                    // L1-hot
                py = pv.y; pz = pv.z; pw = pv.w;
            }
            if (g < 181) {
                f4a sv; sv.x = py; sv.y = pz; sv.z = pw; sv.w = cur.x;
                __builtin_nontemporal_store(sv, reinterpret_cast<f4a*>(orow) + g);
            } else if (g == 181) {                       // lane 53, j=2
                f2a sv; sv.x = py; sv.y = pz;
                __builtin_nontemporal_store(sv, reinterpret_cast<f2a*>(orow + 724));
            }
        }
    } else {
        // ---- halo rows: scalar source map, aligned stores ----
        const unsigned hrow = (blockIdx.x - MIDBLK) * 4u + wid;   // [0, 2304)
        const unsigned hr = hrow % 6u;
        const unsigned bc = hrow / 6u;
        const int ho = (hr < 3u) ? (int)hr : (int)(360u + hr);
        const int h  = (hr < 3u) ? (int)(2u - hr) : (int)(362u - hr);
        const float* __restrict__ srow = x + ((size_t)bc * H + h) * W;
        float* __restrict__ orow = out + ((size_t)bc * Hp + ho) * Wp;

#pragma unroll
        for (int j = 0; j < 3; ++j) {
            const int g = 64 * j + lane;
            const int c0 = 4 * g;
            float v0, v1, v2, v3;
            {
                int wr = c0 + 360;     if (wr >= Wp) wr -= Wp;
                int w  = wr - p; if (w < 0) w += W; else if (w >= W) w -= W;
                v0 = srow[w];
            }
            {
                int wr = c0 + 361;     if (wr >= Wp) wr -= Wp;
                int w  = wr - p; if (w < 0) w += W; else if (w >= W) w -= W;
                v1 = srow[w];
            }
            {
                int wr = c0 + 362;     if (wr >= Wp) wr -= Wp;
                int w  = wr - p; if (w < 0) w += W; else if (w >= W) w -= W;
                v2 = srow[w];
            }
            {
                int wr = c0 + 363;     if (wr >= Wp) wr -= Wp;
                int w  = wr - p; if (w < 0) w += W; else if (w >= W) w -= W;
                v3 = srow[w];
            }
            if (g < 181) {
                f4a sv; sv.x = v0; sv.y = v1; sv.z = v2; sv.w = v3;
                __builtin_nontemporal_store(sv, reinterpret_cast<f4a*>(orow) + g);
            } else if (g == 181) {
                f2a sv; sv.x = v0; sv.y = v1;
                __builtin_nontemporal_store(sv, reinterpret_cast<f2a*>(orow + 724));
            }
        }
    }
}

extern "C" void kernel_launch(void* const* d_in, const int* in_sizes, int n_in,
                              void* d_out, int out_size, void* d_ws, size_t ws_size,
                              hipStream_t stream) {
    const float* x = (const float*)d_in[0];
    float* out = (float*)d_out;

    // 34,560 middle blocks (138,240 rows, wave-per-row)
    // +   576 halo  blocks ( 2,304 rows)
    const unsigned grid = 34560u + 576u;
    geo_pad_kernel<<<grid, 256, 0, stream>>>(x, out);
}

// Round 9
// 142.610 us; speedup vs baseline: 1.1689x; 1.1689x over previous
//
#include <hip/hip_runtime.h>

// GeoCyclicPadding: x (B=2, C=192, H=360, W=720) f32, p=3 -> out (B,C,366,726)
//
// R5 bulk structure (best known: 144 us) + Bresenham interleave of edge
// blocks (R8 fixed: edge job space now consistent with float2 halo groups).
//  BULK (97,200 blocks): out[bc, 3+r, 3+w] = x[bc, r, w] -- thread k copies
//    16B-ALIGNED src group x[bc,r,4k..4k+4) to out[bc,3+r,3+4k..) (store
//    misaligned by 4/12B; R7 proved fixing this costs more than it saves).
//  EDGE (6,507 blocks), per plane EPP = 4338 jobs:
//    q in [0,2160): middle-row edge cols, 1 scalar elem per job
//    q in [2160,4338): halo-row float2 groups (g = q-2160 mod 363,
//                      hr = (q-2160)/363 in [0,6)), wrap fallback
//  Blocks interleaved evenly (edge block every ~16th) so edge work overlaps
//  the bulk BW stream instead of forming a low-BW tail phase.

typedef float f4a __attribute__((ext_vector_type(4), aligned(16)));
typedef float f4u __attribute__((ext_vector_type(4), aligned(4)));
typedef float f2u __attribute__((ext_vector_type(2), aligned(4)));

__global__ __launch_bounds__(256) void geo_pad_kernel(const float* __restrict__ x,
                                                      float* __restrict__ out) {
    constexpr int W = 720, H = 360, p = 3, Wp = 726, Hp = 366;
    constexpr unsigned EPP  = 2160u + 6u * 363u;   // 4338 edge jobs / plane
    constexpr unsigned EBLK = 384u * EPP / 256u;   // 6,507 edge blocks (exact)
    constexpr unsigned TBLK = 97200u + EBLK;       // 103,707 total blocks

    // Bresenham spreading: block i is an edge block iff floor((i+1)E/T)
    // > floor(iE/T); exactly EBLK edge blocks, evenly mixed.
    const unsigned i = blockIdx.x;
    const unsigned long long iE = (unsigned long long)i * EBLK;
    const unsigned e_before = (unsigned)(iE / TBLK);
    const unsigned e_after  = (unsigned)((iE + EBLK) / TBLK);

    if (e_after == e_before) {
        // ---- bulk: aligned-load strided copy (identical to R5) ----
        const unsigned t = (i - e_before) * 256u + threadIdx.x;
        const unsigned k  = t % 180u;
        const unsigned rr = t / 180u;
        const unsigned r  = rr % 360u;
        const unsigned bc = rr / 360u;

        const f4a* src = reinterpret_cast<const f4a*>(
            x + (size_t)(bc * 360u + r) * W) + k;
        f4a v = __builtin_nontemporal_load(src);

        float* dst = out + ((size_t)bc * Hp + (r + 3)) * Wp + 3 + 4 * k;
        f4u sv; sv.x = v.x; sv.y = v.y; sv.z = v.z; sv.w = v.w;
        __builtin_nontemporal_store(sv, reinterpret_cast<f4u*>(dst));
    } else {
        // ---- edges ----
        const unsigned e = e_before * 256u + threadIdx.x;
        const unsigned bc = e / EPP;
        const unsigned q  = e % EPP;

        if (q < 2160u) {                       // middle-row edge columns
            const int r  = (int)(q / 6u);
            const int c6 = (int)(q % 6u);
            const int ho  = r + p;
            const int h   = r;
            const int col = (c6 < 3) ? c6 : (720 + c6);
            const int w   = (c6 < 3) ? (717 + c6) : (c6 - 3);
            out[((size_t)bc * Hp + ho) * Wp + col] =
                x[((size_t)bc * H + h) * W + w];
        } else {                               // halo rows, float2 groups
            const unsigned q2 = q - 2160u;     // [0, 2178)
            const unsigned g  = q2 % 363u;
            const int hr = (int)(q2 / 363u);   // 0..5
            const int ho = (hr < p) ? hr : (H + hr);
            const int h  = (hr < p) ? (p - 1 - hr) : (362 - hr);

            const float* __restrict__ srow = x + ((size_t)bc * H + h) * W;
            float* __restrict__ orow = out + ((size_t)bc * Hp + ho) * Wp;

            const int c0 = 2 * (int)g;
            int wr0 = c0 + 360; if (wr0 >= Wp) wr0 -= Wp;
            int wr1 = c0 + 361; if (wr1 >= Wp) wr1 -= Wp;
            int w0 = wr0 - p; if (w0 < 0) w0 += W; else if (w0 >= W) w0 -= W;
            int w1 = wr1 - p; if (w1 < 0) w1 += W; else if (w1 >= W) w1 -= W;

            f2u sv;
            if (w1 == w0 + 1) {
                sv = *reinterpret_cast<const f2u*>(srow + w0);
            } else {
                sv.x = srow[w0]; sv.y = srow[w1];
            }
            __builtin_nontemporal_store(sv, reinterpret_cast<f2u*>(orow + c0));
        }
    }
}

extern "C" void kernel_launch(void* const* d_in, const int* in_sizes, int n_in,
                              void* d_out, int out_size, void* d_ws, size_t ws_size,
                              hipStream_t stream) {
    const float* x = (const float*)d_in[0];
    float* out = (float*)d_out;

    // 97,200 bulk + 6,507 edge = 103,707 blocks, interleaved in-kernel.
    geo_pad_kernel<<<103707u, 256, 0, stream>>>(x, out);
}